// Round 1
// baseline (252.027 us; speedup 1.0000x reference)
//
#include <hip/hip_runtime.h>
#include <math.h>

// Problem constants: B=128, C=48, H=W=64, p=32, N=4, D=49152
#define PLANE 4096            // 64*64
#define OUT0 25165824         // 128*48*64*64 (flat offset of logdet output)

// ws layout (floats):
#define WS_G    0             // [2304]  G = Wq1^T Wk1 + Wq2^T Wk2 + Wq3^T Wk3
#define WS_PART 2304          // [512*4] partial scores per (b, parity, i-half)
#define WS_ATTN 4352          // [128*8] per-batch coeffs: Ad[4], Ao[4]

// ---------------- k0: G[c][c'] = sum_o Wq[o,c]*Wk[o,c'] over 3 pairs ----------------
__global__ void g_kernel(const float* __restrict__ Wq1, const float* __restrict__ Wq2,
                         const float* __restrict__ Wq3, const float* __restrict__ Wk1,
                         const float* __restrict__ Wk2, const float* __restrict__ Wk3,
                         float* __restrict__ G) {
    int idx = blockIdx.x * 256 + threadIdx.x;
    if (idx >= 2304) return;
    int c = idx / 48, cp = idx % 48;
    float acc = 0.f;
    for (int o = 0; o < 48; ++o) {
        acc = fmaf(Wq1[o * 48 + c], Wk1[o * 48 + cp], acc);
        acc = fmaf(Wq2[o * 48 + c], Wk2[o * 48 + cp], acc);
        acc = fmaf(Wq3[o * 48 + c], Wk3[o * 48 + cp], acc);
    }
    G[idx] = acc;
}

// ---------------- k1: scores via quadratic forms ----------------
// grid 512 = (b:128) x (s:2 parity) x (half:2 i-range); block 256, one pixel/thread.
// Patch top = n=s (h=i), patch bot = n=s+2 (h=i+32); pixel cols w = 32*s + 2*jj + s.
// part[bid][0..3] = Sum v_top^T G v_top, v_top^T G v_bot, v_bot^T G v_top, v_bot^T G v_bot
__global__ __launch_bounds__(256) void score_kernel(const float* __restrict__ x,
                                                    const float* __restrict__ G,
                                                    float* __restrict__ part) {
    int bid = blockIdx.x;
    int b = bid >> 2;
    int s = (bid >> 1) & 1;
    int half = bid & 1;
    int tid = threadIdx.x;
    int i = half * 16 + (tid >> 4);                 // row in patch [0,32)
    int w = 32 * s + ((tid & 15) << 1) + s;         // column with parity s

    const float* xb = x + (size_t)b * (48 * PLANE);
    const float* p1 = xb + i * 64 + w;              // top patch pixel, channel stride PLANE
    const float* p2 = xb + (i + 32) * 64 + w;       // bottom patch pixel

    float v1[48], v2[48];
#pragma unroll
    for (int c = 0; c < 48; ++c) {
        v1[c] = p1[c * PLANE];
        v2[c] = p2[c * PLANE];
    }

    float s11 = 0.f, s12 = 0.f, s21 = 0.f, s22 = 0.f;
    // Fully unrolled so v1[o]/v2[o] are static register accesses; G reads are
    // wave-uniform -> expect s_load scalarization.
#pragma unroll
    for (int o = 0; o < 48; ++o) {
        float u1 = 0.f, u2 = 0.f;
        const float* g = G + o * 48;
#pragma unroll
        for (int c = 0; c < 48; ++c) {
            float gv = g[c];
            u1 = fmaf(gv, v1[c], u1);
            u2 = fmaf(gv, v2[c], u2);
        }
        s11 = fmaf(v1[o], u1, s11);
        s12 = fmaf(v1[o], u2, s12);
        s21 = fmaf(v2[o], u1, s21);
        s22 = fmaf(v2[o], u2, s22);
    }

    // wave reduce (width 64), then cross-wave via LDS
    for (int off = 32; off > 0; off >>= 1) {
        s11 += __shfl_down(s11, off, 64);
        s12 += __shfl_down(s12, off, 64);
        s21 += __shfl_down(s21, off, 64);
        s22 += __shfl_down(s22, off, 64);
    }
    __shared__ float red[4][4];
    int wid = tid >> 6;
    if ((tid & 63) == 0) {
        red[0][wid] = s11; red[1][wid] = s12; red[2][wid] = s21; red[3][wid] = s22;
    }
    __syncthreads();
    if (tid < 4) {
        part[bid * 4 + tid] = red[tid][0] + red[tid][1] + red[tid][2] + red[tid][3];
    }
}

// ---------------- k2: per-batch softmax, attn coeffs, logdet ----------------
// Row n (parity P) softmax over [s_same1, 0, s_same2, 0] (+offset3 cancels).
__global__ void attn_kernel(const float* __restrict__ part, const float* __restrict__ logdet_in,
                            const float* __restrict__ off_p, const float* __restrict__ off2_p,
                            float* __restrict__ attn_ws, float* __restrict__ out_logdet) {
    int b = blockIdx.x * blockDim.x + threadIdx.x;
    if (b >= 128) return;
    const float inv_scale = 1.0f / sqrtf(49152.0f);
    float off = off_p[0];
    float c2 = off2_p[0];
    float ld = 0.f;
    float Ad[4], Ao[4];
#pragma unroll
    for (int s = 0; s < 2; ++s) {
        int base0 = (b * 4 + s * 2) * 4;
        int base1 = base0 + 4;
        float stt = (part[base0 + 0] + part[base1 + 0]) * inv_scale;  // (top,top)
        float stb = (part[base0 + 1] + part[base1 + 1]) * inv_scale;  // (top,bot)
        float sbt = (part[base0 + 2] + part[base1 + 2]) * inv_scale;  // (bot,top)
        float sbb = (part[base0 + 3] + part[base1 + 3]) * inv_scale;  // (bot,bot)

        // row top: entries {stt, stb, 0, 0}; two exp(0) terms in denominator
        float m0 = fmaxf(fmaxf(stt, stb), 0.f);
        float e00 = expf(stt - m0), e01 = expf(stb - m0), ez0 = expf(-m0);
        float d0 = e00 + e01 + 2.f * ez0;
        float ptt = e00 / d0, ptb = e01 / d0;
        // row bot: entries {sbt, sbb, 0, 0}
        float m1 = fmaxf(fmaxf(sbt, sbb), 0.f);
        float e10 = expf(sbt - m1), e11 = expf(sbb - m1), ez1 = expf(-m1);
        float d1 = e10 + e11 + 2.f * ez1;
        float pbt = e10 / d1, pbb = e11 / d1;

        float adt = ptt + c2 + off;   // attn[top][top] + off (diag)
        float aot = ptb + c2;         // attn[top][bot]
        float adb = pbb + c2 + off;   // attn[bot][bot] + off
        float aob = pbt + c2;         // attn[bot][top]
        Ad[s] = adt; Ao[s] = aot; Ad[s + 2] = adb; Ao[s + 2] = aob;
        float det = adt * adb - aot * aob;
        ld += logf(fabsf(det));
    }
#pragma unroll
    for (int n = 0; n < 4; ++n) {
        attn_ws[b * 8 + n] = Ad[n];
        attn_ws[b * 8 + 4 + n] = Ao[n];
    }
    out_logdet[b] = logdet_in[b] + ld * 24576.0f;
}

// ---------------- k3: streaming output ----------------
// out[b,c,h,w]: e=(wb+w)&1; e==0 -> x; e==1 -> Ad[n]*x[h] + Ao[n]*x[h^32] with n=2*hb+wb.
// Each thread owns an (h, h+32) float4 pair so x is read exactly once.
__global__ __launch_bounds__(256) void out_kernel(const float* __restrict__ x,
                                                  const float* __restrict__ attn_ws,
                                                  float* __restrict__ out) {
    int bc = blockIdx.x;            // 128*48
    int b = bc / 48;
    const float* A = attn_ws + b * 8;
    float Ad0 = A[0], Ad1 = A[1], Ad2 = A[2], Ad3 = A[3];
    float Ao0 = A[4], Ao1 = A[5], Ao2 = A[6], Ao3 = A[7];

    const float4* xb = (const float4*)(x + (size_t)bc * PLANE);
    float4* ob = (float4*)(out + (size_t)bc * PLANE);
    int tid = threadIdx.x;
#pragma unroll
    for (int it = 0; it < 2; ++it) {
        int f = it * 256 + tid;       // 0..511
        int h = f >> 4;               // 0..31
        int w4 = f & 15;
        float4 xt = xb[h * 16 + w4];
        float4 xv = xb[(h + 32) * 16 + w4];
        int wb = w4 >> 3;             // 0: w<32, 1: w>=32
        float Adt = wb ? Ad1 : Ad0;   // n_top = wb
        float Aot = wb ? Ao1 : Ao0;
        float Adb = wb ? Ad3 : Ad2;   // n_bot = wb + 2
        float Aob = wb ? Ao3 : Ao2;

        float t[4] = {xt.x, xt.y, xt.z, xt.w};
        float v[4] = {xv.x, xv.y, xv.z, xv.w};
        float ot[4], ov[4];
#pragma unroll
        for (int q = 0; q < 4; ++q) {
            int e = (wb + q) & 1;     // w component parity: (wb + 4*w4 + q)&1
            float mt = fmaf(Adt, t[q], Aot * v[q]);
            float mv = fmaf(Adb, v[q], Aob * t[q]);
            ot[q] = e ? mt : t[q];
            ov[q] = e ? mv : v[q];
        }
        float4 rt = {ot[0], ot[1], ot[2], ot[3]};
        float4 rv = {ov[0], ov[1], ov[2], ov[3]};
        ob[h * 16 + w4] = rt;
        ob[(h + 32) * 16 + w4] = rv;
    }
}

extern "C" void kernel_launch(void* const* d_in, const int* in_sizes, int n_in,
                              void* d_out, int out_size, void* d_ws, size_t ws_size,
                              hipStream_t stream) {
    const float* x      = (const float*)d_in[0];
    const float* logdet = (const float*)d_in[1];
    const float* Wq1    = (const float*)d_in[2];
    const float* Wq2    = (const float*)d_in[3];
    const float* Wq3    = (const float*)d_in[4];
    const float* Wk1    = (const float*)d_in[5];
    const float* Wk2    = (const float*)d_in[6];
    const float* Wk3    = (const float*)d_in[7];
    const float* off    = (const float*)d_in[8];
    const float* off2   = (const float*)d_in[9];
    // d_in[10] (offset3) is a uniform pre-softmax shift -> cancels; unused.

    float* out = (float*)d_out;
    float* ws  = (float*)d_ws;
    float* G    = ws + WS_G;
    float* part = ws + WS_PART;
    float* attn = ws + WS_ATTN;

    g_kernel<<<9, 256, 0, stream>>>(Wq1, Wq2, Wq3, Wk1, Wk2, Wk3, G);
    score_kernel<<<512, 256, 0, stream>>>(x, G, part);
    attn_kernel<<<1, 128, 0, stream>>>(part, logdet, off, off2, attn, out + OUT0);
    out_kernel<<<6144, 256, 0, stream>>>(x, attn, out);
}

// Round 3
// 242.196 us; speedup vs baseline: 1.0406x; 1.0406x over previous
//
#include <hip/hip_runtime.h>
#include <math.h>

// Problem constants: B=128, C=48, H=W=64, p=32, N=4, D=49152
#define PLANE 4096            // 64*64
#define OUT0 25165824         // 128*48*64*64 (flat offset of logdet output)

typedef float fx4 __attribute__((ext_vector_type(4)));   // native vec for NT load/store

// ws layout (floats):
#define WS_GT   0             // [2304]  GT[k*48+r] = G[r][k] = sum_o Wq[o,r]*Wk[o,k] (3 pairs)
#define WS_PART 2304          // [512*4] partial scores per (b, parity, i-half)

// ---------------- k0: GT[k][r] = sum_o Wq[o,r]*Wk[o,k] over 3 pairs (transposed G) ----
__global__ void g_kernel(const float* __restrict__ Wq1, const float* __restrict__ Wq2,
                         const float* __restrict__ Wq3, const float* __restrict__ Wk1,
                         const float* __restrict__ Wk2, const float* __restrict__ Wk3,
                         float* __restrict__ GT) {
    int idx = blockIdx.x * 256 + threadIdx.x;
    if (idx >= 2304) return;
    int k = idx / 48, r = idx % 48;   // GT[k*48+r] = G[r][k]
    float acc = 0.f;
    for (int o = 0; o < 48; ++o) {
        acc = fmaf(Wq1[o * 48 + r], Wk1[o * 48 + k], acc);
        acc = fmaf(Wq2[o * 48 + r], Wk2[o * 48 + k], acc);
        acc = fmaf(Wq3[o * 48 + r], Wk3[o * 48 + k], acc);
    }
    GT[idx] = acc;
}

// ---------------- k1: scores via quadratic forms, k-outer accumulator form ----------
// grid 512 = (b:128) x (s:2 parity) x (half:2 i-range); block 256, one pixel-pair/thread.
// u1[r] = sum_k G[r,k] v1[k]  (u arrays are accumulators -> pinned in VGPRs, ~96 regs)
// G read at wave-uniform addresses -> s_load scalarization (scalar pipe, no VALU cost).
// v streamed with depth-2 prefetch; final dot reloads v (L1/L2 hits mostly).
__global__ __launch_bounds__(256, 2) void score_kernel(const float* __restrict__ x,
                                                       const float* __restrict__ GT,
                                                       float* __restrict__ part) {
    int bid = blockIdx.x;
    int b = bid >> 2;
    int s = (bid >> 1) & 1;
    int half = bid & 1;
    int tid = threadIdx.x;
    int i = half * 16 + (tid >> 4);                 // row in patch [0,32)
    int w = 32 * s + ((tid & 15) << 1) + s;         // column with parity s

    const float* xb = x + (size_t)b * (48 * PLANE);
    const float* p1 = xb + i * 64 + w;              // top patch pixel, channel stride PLANE
    const float* p2 = xb + (i + 32) * 64 + w;       // bottom patch pixel

    float u1[48], u2[48];
#pragma unroll
    for (int r = 0; r < 48; ++r) { u1[r] = 0.f; u2[r] = 0.f; }

    // software pipeline depth 2 over channel index k
    float t0 = p1[0],     v0 = p2[0];
    float t1 = p1[PLANE], v1 = p2[PLANE];
    for (int k = 0; k < 48; k += 2) {
        float t2 = 0.f, v2 = 0.f, t3 = 0.f, v3 = 0.f;
        if (k + 3 < 48) {
            t2 = p1[(k + 2) * PLANE]; v2 = p2[(k + 2) * PLANE];
            t3 = p1[(k + 3) * PLANE]; v3 = p2[(k + 3) * PLANE];
        }
        const float* g0 = GT + k * 48;         // wave-uniform -> s_load
        const float* g1 = GT + (k + 1) * 48;
#pragma unroll
        for (int r = 0; r < 48; ++r) {
            float ga = g0[r];
            float gb = g1[r];
            u1[r] = fmaf(ga, t0, u1[r]);
            u2[r] = fmaf(ga, v0, u2[r]);
            u1[r] = fmaf(gb, t1, u1[r]);
            u2[r] = fmaf(gb, v1, u2[r]);
        }
        t0 = t2; v0 = v2; t1 = t3; v1 = v3;
    }

    // final dot: s_ij = v_i . u_j ; v reloaded (L1/L2-warm). MUST fully unroll so
    // u1[r]/u2[r] stay static register references.
    float s11 = 0.f, s12 = 0.f, s21 = 0.f, s22 = 0.f;
#pragma unroll
    for (int r = 0; r < 48; ++r) {
        float a = p1[r * PLANE];
        float c = p2[r * PLANE];
        s11 = fmaf(a, u1[r], s11);
        s12 = fmaf(a, u2[r], s12);
        s21 = fmaf(c, u1[r], s21);
        s22 = fmaf(c, u2[r], s22);
    }

    // wave reduce (width 64), then cross-wave via LDS
    for (int off = 32; off > 0; off >>= 1) {
        s11 += __shfl_down(s11, off, 64);
        s12 += __shfl_down(s12, off, 64);
        s21 += __shfl_down(s21, off, 64);
        s22 += __shfl_down(s22, off, 64);
    }
    __shared__ float red[4][4];
    int wid = tid >> 6;
    if ((tid & 63) == 0) {
        red[0][wid] = s11; red[1][wid] = s12; red[2][wid] = s21; red[3][wid] = s22;
    }
    __syncthreads();
    if (tid < 4) {
        part[bid * 4 + tid] = red[tid][0] + red[tid][1] + red[tid][2] + red[tid][3];
    }
}

// ---------------- k2: streaming output + fused attn/softmax/logdet ----------------
// Each block redundantly computes its batch's 8 attn coeffs from part[] (16 floats,
// uniform -> scalarized); block with c==0 writes logdet. Then streams the transform:
// out[b,c,h,w]: e=(wb+w)&1; e==0 -> x; e==1 -> Ad[n]*x[h] + Ao[n]*x[h^32], n=2*hb+wb.
__global__ __launch_bounds__(256) void out_kernel(const float* __restrict__ x,
                                                  const float* __restrict__ part,
                                                  const float* __restrict__ logdet_in,
                                                  const float* __restrict__ off_p,
                                                  const float* __restrict__ off2_p,
                                                  float* __restrict__ out,
                                                  float* __restrict__ out_logdet) {
    int bc = blockIdx.x;            // 128*48
    int b = bc / 48;

    const float inv_scale = 4.5105361e-3f;   // 1/sqrt(49152)
    float off = off_p[0];
    float c2o = off2_p[0];
    float ld = 0.f;
    float Ad[4], Ao[4];
#pragma unroll
    for (int s = 0; s < 2; ++s) {
        int base0 = (b * 4 + s * 2) * 4;
        int base1 = base0 + 4;
        float stt = (part[base0 + 0] + part[base1 + 0]) * inv_scale;
        float stb = (part[base0 + 1] + part[base1 + 1]) * inv_scale;
        float sbt = (part[base0 + 2] + part[base1 + 2]) * inv_scale;
        float sbb = (part[base0 + 3] + part[base1 + 3]) * inv_scale;

        float m0 = fmaxf(fmaxf(stt, stb), 0.f);
        float e00 = expf(stt - m0), e01 = expf(stb - m0), ez0 = expf(-m0);
        float d0 = e00 + e01 + 2.f * ez0;
        float ptt = e00 / d0, ptb = e01 / d0;
        float m1 = fmaxf(fmaxf(sbt, sbb), 0.f);
        float e10 = expf(sbt - m1), e11 = expf(sbb - m1), ez1 = expf(-m1);
        float d1 = e10 + e11 + 2.f * ez1;
        float pbt = e10 / d1, pbb = e11 / d1;

        float adt = ptt + c2o + off;
        float aot = ptb + c2o;
        float adb = pbb + c2o + off;
        float aob = pbt + c2o;
        Ad[s] = adt; Ao[s] = aot; Ad[s + 2] = adb; Ao[s + 2] = aob;
        float det = adt * adb - aot * aob;
        ld += logf(fabsf(det));
    }
    if ((bc - b * 48) == 0 && threadIdx.x == 0) {
        out_logdet[b] = logdet_in[b] + ld * 24576.0f;
    }

    const fx4* xb4 = (const fx4*)(x + (size_t)bc * PLANE);
    fx4* ob4 = (fx4*)(out + (size_t)bc * PLANE);
    int tid = threadIdx.x;
#pragma unroll
    for (int it = 0; it < 2; ++it) {
        int f = it * 256 + tid;       // 0..511
        int h = f >> 4;               // 0..31
        int w4 = f & 15;
        fx4 xt = xb4[h * 16 + w4];
        fx4 xv = xb4[(h + 32) * 16 + w4];
        int wb = w4 >> 3;             // 0: w<32, 1: w>=32
        float Adt = wb ? Ad[1] : Ad[0];
        float Aot = wb ? Ao[1] : Ao[0];
        float Adb = wb ? Ad[3] : Ad[2];
        float Aob = wb ? Ao[3] : Ao[2];

        fx4 rt, rv;
#pragma unroll
        for (int q = 0; q < 4; ++q) {
            int e = (wb + q) & 1;     // w component parity
            float t = xt[q], v = xv[q];
            float mt = fmaf(Adt, t, Aot * v);
            float mv = fmaf(Adb, v, Aob * t);
            rt[q] = e ? mt : t;
            rv[q] = e ? mv : v;
        }
        __builtin_nontemporal_store(rt, &ob4[h * 16 + w4]);
        __builtin_nontemporal_store(rv, &ob4[(h + 32) * 16 + w4]);
    }
}

extern "C" void kernel_launch(void* const* d_in, const int* in_sizes, int n_in,
                              void* d_out, int out_size, void* d_ws, size_t ws_size,
                              hipStream_t stream) {
    const float* x      = (const float*)d_in[0];
    const float* logdet = (const float*)d_in[1];
    const float* Wq1    = (const float*)d_in[2];
    const float* Wq2    = (const float*)d_in[3];
    const float* Wq3    = (const float*)d_in[4];
    const float* Wk1    = (const float*)d_in[5];
    const float* Wk2    = (const float*)d_in[6];
    const float* Wk3    = (const float*)d_in[7];
    const float* off    = (const float*)d_in[8];
    const float* off2   = (const float*)d_in[9];
    // d_in[10] (offset3) is a uniform pre-softmax shift -> cancels; unused.

    float* out = (float*)d_out;
    float* ws  = (float*)d_ws;
    float* GT   = ws + WS_GT;
    float* part = ws + WS_PART;

    g_kernel<<<9, 256, 0, stream>>>(Wq1, Wq2, Wq3, Wk1, Wk2, Wk3, GT);
    score_kernel<<<512, 256, 0, stream>>>(x, GT, part);
    out_kernel<<<6144, 256, 0, stream>>>(x, part, logdet, off, off2, out, out + OUT0);
}

// Round 4
// 227.552 us; speedup vs baseline: 1.1076x; 1.0644x over previous
//
#include <hip/hip_runtime.h>
#include <math.h>

// Problem constants: B=128, C=48, H=W=64, p=32, N=4, D=49152
#define PLANE 4096            // 64*64
#define OUT0 25165824         // 128*48*64*64 (flat offset of logdet output)

typedef float fx4 __attribute__((ext_vector_type(4)));   // native vec for NT/LDS vec ops

// ws layout (floats):
#define WS_GT   0             // [2304]  GT[k*48+r] = G[r][k] = sum_o Wq[o,r]*Wk[o,k] (3 pairs)
#define WS_PART 4096          // [128*2*4] score sums per (b, s): {s11,s12,s21,s22}

// ---------------- k0: GT[k][r] = sum_o Wq[o,r]*Wk[o,k] over 3 pairs (transposed G) ----
__global__ void g_kernel(const float* __restrict__ Wq1, const float* __restrict__ Wq2,
                         const float* __restrict__ Wq3, const float* __restrict__ Wk1,
                         const float* __restrict__ Wk2, const float* __restrict__ Wk3,
                         float* __restrict__ GT) {
    int idx = blockIdx.x * 256 + threadIdx.x;
    if (idx >= 2304) return;
    int k = idx / 48, r = idx % 48;   // GT[k*48+r] = G[r][k]
    float acc = 0.f;
    for (int o = 0; o < 48; ++o) {
        acc = fmaf(Wq1[o * 48 + r], Wk1[o * 48 + k], acc);
        acc = fmaf(Wq2[o * 48 + r], Wk2[o * 48 + k], acc);
        acc = fmaf(Wq3[o * 48 + r], Wk3[o * 48 + k], acc);
    }
    GT[idx] = acc;
}

// ---------------- k1: scores via r-split quadratic forms ----------
// grid 2048 = (b:128) x (s:2) x (g:8 pixel-groups); block 256 = 64 pixel-pairs x 4 r-chunks.
// Thread (pix, rc) accumulates u{1,2}[j] = sum_k G[rc*12+j, k] * v{1,2}[k] (24 accums),
// captures its own chunk of v{1,2} from the k-stream via cndmask (no reload pass),
// then dots, butterfly-reduces across the wave, and atomically adds into part[].
// G lives in LDS: quad lanes read identical 48B rows -> ds_read_b128 broadcast.
__global__ __launch_bounds__(256) void score_kernel(const float* __restrict__ x,
                                                    const float* __restrict__ GT,
                                                    float* __restrict__ part) {
    __shared__ float Gs[2304];
    __shared__ float red[4][4];
    int tid = threadIdx.x;
    for (int idx = tid; idx < 2304; idx += 256) Gs[idx] = GT[idx];
    __syncthreads();

    int bid = blockIdx.x;
    int g = bid & 7;
    int s = (bid >> 3) & 1;
    int b = bid >> 4;
    int pix = tid >> 2;                 // 0..63
    int rc = tid & 3;                   // r-chunk: rows rc*12 .. rc*12+11
    int pp = g * 64 + pix;              // 0..511 pixel-pair within (b,s)
    int i = pp >> 4;                    // row in patch [0,32)
    int jj = pp & 15;
    int w = 32 * s + (jj << 1) + s;     // column with parity s

    const float* p1 = x + (size_t)b * (48 * PLANE) + i * 64 + w;   // top (n=s)
    const float* p2 = p1 + 32 * 64;                                 // bottom (n=s+2)

    float u1[12], u2[12], a1[12], a2[12];
#pragma unroll
    for (int j = 0; j < 12; ++j) { u1[j] = 0.f; u2[j] = 0.f; a1[j] = 0.f; a2[j] = 0.f; }

    const fx4* gbase = (const fx4*)(Gs + rc * 12);   // 48B-aligned

#pragma unroll
    for (int k = 0; k < 48; ++k) {
        float t = p1[k * PLANE];
        float v = p2[k * PLANE];
        fx4 gA = gbase[k * 12 + 0];   // Gs[k*48 + rc*12 + 0..3]
        fx4 gB = gbase[k * 12 + 1];
        fx4 gC = gbase[k * 12 + 2];
#pragma unroll
        for (int j = 0; j < 4; ++j) {
            u1[j]     = fmaf(gA[j], t, u1[j]);
            u2[j]     = fmaf(gA[j], v, u2[j]);
            u1[j + 4] = fmaf(gB[j], t, u1[j + 4]);
            u2[j + 4] = fmaf(gB[j], v, u2[j + 4]);
            u1[j + 8] = fmaf(gC[j], t, u1[j + 8]);
            u2[j + 8] = fmaf(gC[j], v, u2[j + 8]);
        }
        // capture v into this thread's chunk registers when k is in-chunk
        const int q = k / 12, j0 = k % 12;
        bool m = (rc == q);
        a1[j0] = m ? t : a1[j0];
        a2[j0] = m ? v : a2[j0];
    }

    float s11 = 0.f, s12 = 0.f, s21 = 0.f, s22 = 0.f;
#pragma unroll
    for (int j = 0; j < 12; ++j) {
        s11 = fmaf(a1[j], u1[j], s11);
        s12 = fmaf(a1[j], u2[j], s12);
        s21 = fmaf(a2[j], u1[j], s21);
        s22 = fmaf(a2[j], u2[j], s22);
    }

    // full-wave butterfly: sums over the 4 r-chunks AND the wave's 16 pixels
    for (int off = 1; off < 64; off <<= 1) {
        s11 += __shfl_xor(s11, off, 64);
        s12 += __shfl_xor(s12, off, 64);
        s21 += __shfl_xor(s21, off, 64);
        s22 += __shfl_xor(s22, off, 64);
    }
    int wid = tid >> 6;
    if ((tid & 63) == 0) {
        red[wid][0] = s11; red[wid][1] = s12; red[wid][2] = s21; red[wid][3] = s22;
    }
    __syncthreads();
    if (tid < 4) {
        float tot = red[0][tid] + red[1][tid] + red[2][tid] + red[3][tid];
        atomicAdd(&part[(b * 2 + s) * 4 + tid], tot);
    }
}

// ---------------- k2: streaming output + fused attn/softmax/logdet ----------------
// out[b,c,h,w]: e=(wb+w)&1; e==0 -> x; e==1 -> Ad[n]*x[h] + Ao[n]*x[h^32], n=2*hb+wb.
__global__ __launch_bounds__(256) void out_kernel(const float* __restrict__ x,
                                                  const float* __restrict__ part,
                                                  const float* __restrict__ logdet_in,
                                                  const float* __restrict__ off_p,
                                                  const float* __restrict__ off2_p,
                                                  float* __restrict__ out,
                                                  float* __restrict__ out_logdet) {
    int bc = blockIdx.x;            // 128*48
    int b = bc / 48;

    const float inv_scale = 4.5105361e-3f;   // 1/sqrt(49152)
    float off = off_p[0];
    float c2o = off2_p[0];
    float ld = 0.f;
    float Ad[4], Ao[4];
#pragma unroll
    for (int s = 0; s < 2; ++s) {
        int base = (b * 2 + s) * 4;
        float stt = part[base + 0] * inv_scale;   // (top,top)
        float stb = part[base + 1] * inv_scale;   // (top,bot)
        float sbt = part[base + 2] * inv_scale;   // (bot,top)
        float sbb = part[base + 3] * inv_scale;   // (bot,bot)

        float m0 = fmaxf(fmaxf(stt, stb), 0.f);
        float e00 = expf(stt - m0), e01 = expf(stb - m0), ez0 = expf(-m0);
        float d0 = e00 + e01 + 2.f * ez0;
        float ptt = e00 / d0, ptb = e01 / d0;
        float m1 = fmaxf(fmaxf(sbt, sbb), 0.f);
        float e10 = expf(sbt - m1), e11 = expf(sbb - m1), ez1 = expf(-m1);
        float d1 = e10 + e11 + 2.f * ez1;
        float pbt = e10 / d1, pbb = e11 / d1;

        float adt = ptt + c2o + off;
        float aot = ptb + c2o;
        float adb = pbb + c2o + off;
        float aob = pbt + c2o;
        Ad[s] = adt; Ao[s] = aot; Ad[s + 2] = adb; Ao[s + 2] = aob;
        float det = adt * adb - aot * aob;
        ld += logf(fabsf(det));
    }
    if ((bc - b * 48) == 0 && threadIdx.x == 0) {
        out_logdet[b] = logdet_in[b] + ld * 24576.0f;
    }

    const fx4* xb4 = (const fx4*)(x + (size_t)bc * PLANE);
    fx4* ob4 = (fx4*)(out + (size_t)bc * PLANE);
    int tid = threadIdx.x;
#pragma unroll
    for (int it = 0; it < 2; ++it) {
        int f = it * 256 + tid;       // 0..511
        int h = f >> 4;               // 0..31
        int w4 = f & 15;
        fx4 xt = xb4[h * 16 + w4];
        fx4 xv = xb4[(h + 32) * 16 + w4];
        int wb = w4 >> 3;             // 0: w<32, 1: w>=32
        float Adt = wb ? Ad[1] : Ad[0];
        float Aot = wb ? Ao[1] : Ao[0];
        float Adb = wb ? Ad[3] : Ad[2];
        float Aob = wb ? Ao[3] : Ao[2];

        fx4 rt, rv;
#pragma unroll
        for (int q = 0; q < 4; ++q) {
            int e = (wb + q) & 1;     // w component parity
            float t = xt[q], v = xv[q];
            float mt = fmaf(Adt, t, Aot * v);
            float mv = fmaf(Adb, v, Aob * t);
            rt[q] = e ? mt : t;
            rv[q] = e ? mv : v;
        }
        __builtin_nontemporal_store(rt, &ob4[h * 16 + w4]);
        __builtin_nontemporal_store(rv, &ob4[(h + 32) * 16 + w4]);
    }
}

extern "C" void kernel_launch(void* const* d_in, const int* in_sizes, int n_in,
                              void* d_out, int out_size, void* d_ws, size_t ws_size,
                              hipStream_t stream) {
    const float* x      = (const float*)d_in[0];
    const float* logdet = (const float*)d_in[1];
    const float* Wq1    = (const float*)d_in[2];
    const float* Wq2    = (const float*)d_in[3];
    const float* Wq3    = (const float*)d_in[4];
    const float* Wk1    = (const float*)d_in[5];
    const float* Wk2    = (const float*)d_in[6];
    const float* Wk3    = (const float*)d_in[7];
    const float* off    = (const float*)d_in[8];
    const float* off2   = (const float*)d_in[9];
    // d_in[10] (offset3) is a uniform pre-softmax shift -> cancels; unused.

    float* out = (float*)d_out;
    float* ws  = (float*)d_ws;
    float* GT   = ws + WS_GT;
    float* part = ws + WS_PART;

    hipMemsetAsync(part, 0, 128 * 2 * 4 * sizeof(float), stream);
    g_kernel<<<9, 256, 0, stream>>>(Wq1, Wq2, Wq3, Wk1, Wk2, Wk3, GT);
    score_kernel<<<2048, 256, 0, stream>>>(x, GT, part);
    out_kernel<<<6144, 256, 0, stream>>>(x, part, logdet, off, off2, out, out + OUT0);
}